// Round 1
// baseline (127.007 us; speedup 1.0000x reference)
//
#include <hip/hip_runtime.h>
#include <math.h>

#define BB 2
#define LL 1024
#define HH 8
#define DD 64
#define SS 10
#define RR 128
// K dimension = D * 2S = 1280, split into 20 blocks of 64

typedef short bf16x8 __attribute__((ext_vector_type(8)));
typedef float f32x16 __attribute__((ext_vector_type(16)));

// round-to-nearest bf16 lives in high 16 bits after this add
__device__ __forceinline__ unsigned int rnd_bf16(float x) {
    union { float f; unsigned int u; } v; v.f = x;
    return v.u + 0x8000u;
}
// pack bf16(c) into low half, bf16(s) into high half (c at lower address)
__device__ __forceinline__ unsigned int pack_bf16(float c, float s) {
    return __builtin_amdgcn_perm(rnd_bf16(s), rnd_bf16(c), 0x07060302u);
}

__global__ __launch_bounds__(256) void prep_params(
    const float* __restrict__ freqs, const float* __restrict__ offsets,
    float* __restrict__ frp, float* __restrict__ offp)
{
    int i = blockIdx.x * 256 + threadIdx.x;
    if (i < HH * DD * SS) {
        float f = freqs[i];
        frp[i]  = 0.5f / (1.0f + __expf(-f));          // sigmoid(f)/2, revolutions/step
        offp[i] = offsets[i] * 0.15915494309189535f;   // offsets / 2pi
    }
}

// zs tile layout: per (bh, kb): [r=0..127][kkl=0..63] bf16, contiguous 16KB
__global__ __launch_bounds__(256) void prep_z(
    const float* __restrict__ gains, const float* __restrict__ z,
    unsigned short* __restrict__ zt)
{
    const float scale = 0.011048543456039806f;  // 1/sqrt(R*D)
    int bid = blockIdx.x;           // 0..319
    int bh = bid / 20, kb = bid % 20;
    int h = bh & 7;
    int t = threadIdx.x;
    __shared__ unsigned short tr[128 * 65];

    for (int i = 0; i < 32; i++) {
        int e = i * 256 + t;        // e = kkl*128 + r  (coalesced on r)
        int kkl = e >> 7, r = e & 127;
        int kkg = kb * 64 + kkl;
        int d = kkg / 20, j = kkg - d * 20;
        int jm = (j < 10) ? j : j - 10;            // concat([g,g]) layout
        float gn = gains[(h * 64 + d) * 10 + jm];
        float g = fmaxf(gn, 0.0f) + log1pf(__expf(-fabsf(gn)));  // softplus
        float val = z[((size_t)bh * 1280 + kkg) * 128 + r] * g * scale;
        tr[r * 65 + kkl] = (unsigned short)(rnd_bf16(val) >> 16);
    }
    __syncthreads();
    size_t obase = (size_t)bid * 8192;
    for (int i = 0; i < 32; i++) {
        int e2 = i * 256 + t;       // e2 = r*64 + kkl (coalesced write)
        int r = e2 >> 6, kkl = e2 & 63;
        zt[obase + e2] = tr[r * 65 + kkl];
    }
}

__global__ __launch_bounds__(256, 1) void spe_gemm(
    const float* __restrict__ queries, const float* __restrict__ keys,
    const float* __restrict__ frp, const float* __restrict__ offp,
    const unsigned short* __restrict__ zt, float* __restrict__ out)
{
    // padded LDS: A/Z stride 72 bf16 (144B) -> 2-way bank aliasing only
    __shared__ __align__(16) unsigned short Asm[128 * 72];
    __shared__ __align__(16) unsigned short Zsm[128 * 72];
    __shared__ __align__(8)  unsigned short Qsm[128 * 68];

    int bid = blockIdx.x;
    int bh = bid & 15;              // bid%8 == f(bh): same-bh blocks share XCD
    int mtile = bid >> 4;           // 0..15 over stacked M=[q(8 tiles); k(8 tiles)]
    int b = bh >> 3, h = bh & 7;
    bool isQ = (mtile < 8);
    int l0 = (mtile & 7) * 128;

    int t = threadIdx.x;
    int lane = t & 63;
    int w = t >> 6;
    int wm = w >> 1, wn = w & 1;

    const float* src = isQ ? queries : keys;

    // ---- stage Q tile (bf16): Qsm[row][d], stride 68 ----
    #pragma unroll
    for (int i = 0; i < 8; i++) {
        int e4 = i * 256 + t;                  // 2048 float4 = 8192 floats
        int row = e4 >> 4, dq = (e4 & 15) * 4;
        float4 qv = *(const float4*)(src + (((size_t)(b * 1024 + l0 + row) * 8 + h) * 64 + dq));
        unsigned int p0 = __builtin_amdgcn_perm(rnd_bf16(qv.y), rnd_bf16(qv.x), 0x07060302u);
        unsigned int p1 = __builtin_amdgcn_perm(rnd_bf16(qv.w), rnd_bf16(qv.z), 0x07060302u);
        *(uint2*)((char*)Qsm + row * 136 + dq * 2) = make_uint2(p0, p1);
    }

    f32x16 acc[2][2] = {};

    int rowA = t >> 1;                 // A-construction: 2 threads per row
    int half = t & 1;                  // each covers 32 kk = 16 cos/sin pairs
    float lf = (float)(l0 + rowA);
    const unsigned int abase = (unsigned int)rowA * 144 + (unsigned int)half * 64;
    const int qrow = rowA * 68;

    for (int kb = 0; kb < 20; kb++) {
        __syncthreads();   // covers Q-stage on iter0; protects A/Z overwrite after

        // ---- compute A tile: A[row][kkl] = omega(h,d,l,j)*q ----
        const float* frb = frp + h * 640 + kb * 32 + half * 16;
        float frr[16], ofr[16];
        #pragma unroll
        for (int i = 0; i < 4; i++) ((float4*)frr)[i] = ((const float4*)frb)[i];
        if (isQ) {
            const float* ofb = offp + h * 640 + kb * 32 + half * 16;
            #pragma unroll
            for (int i = 0; i < 4; i++) ((float4*)ofr)[i] = ((const float4*)ofb)[i];
        } else {
            #pragma unroll
            for (int i = 0; i < 16; i++) ofr[i] = 0.0f;
        }
        int pp0 = kb * 32 + half * 16;
        #pragma unroll
        for (int p = 0; p < 16; p++) {
            int pp = pp0 + p;
            int d = pp / 10;                       // pair index -> d
            float tre = fmaf(frr[p], lf, ofr[p]);  // revolutions
            tre = tre - floorf(tre);               // fract -> [0,1)
            float rad = 6.28318530717958648f * tre;
            unsigned int qu = (unsigned int)Qsm[qrow + d] << 16;
            float qv = __builtin_bit_cast(float, qu);
            float cv = __cosf(rad) * qv;
            float sv = __sinf(rad) * qv;
            ((unsigned int*)((char*)Asm + abase))[p] = pack_bf16(cv, sv);
        }

        // ---- stage Z tile: Zsm[r][kkl] from contiguous 16KB tile ----
        const uint4* ztile = (const uint4*)(zt + (size_t)(bh * 20 + kb) * 8192);
        #pragma unroll
        for (int i = 0; i < 4; i++) {
            int e16 = i * 256 + t;                 // 1024 uint4 per tile
            uint4 v = ztile[e16];
            int r = e16 >> 3, k8 = e16 & 7;
            *(uint4*)((char*)Zsm + r * 144 + k8 * 16) = v;
        }

        __syncthreads();

        // ---- MFMA: 2x2 wave tiles of 64x64, 32x32x16 bf16 ----
        #pragma unroll
        for (int ks = 0; ks < 4; ks++) {
            int koff = ks * 32 + ((lane >> 5) << 4);
            int m0 = wm * 64 + (lane & 31);
            int n0 = wn * 64 + (lane & 31);
            bf16x8 a0 = *(const bf16x8*)((const char*)Asm + m0 * 144 + koff);
            bf16x8 a1 = *(const bf16x8*)((const char*)Asm + (m0 + 32) * 144 + koff);
            bf16x8 b0 = *(const bf16x8*)((const char*)Zsm + n0 * 144 + koff);
            bf16x8 b1 = *(const bf16x8*)((const char*)Zsm + (n0 + 32) * 144 + koff);
            acc[0][0] = __builtin_amdgcn_mfma_f32_32x32x16_bf16(a0, b0, acc[0][0], 0, 0, 0);
            acc[0][1] = __builtin_amdgcn_mfma_f32_32x32x16_bf16(a0, b1, acc[0][1], 0, 0, 0);
            acc[1][0] = __builtin_amdgcn_mfma_f32_32x32x16_bf16(a1, b0, acc[1][0], 0, 0, 0);
            acc[1][1] = __builtin_amdgcn_mfma_f32_32x32x16_bf16(a1, b1, acc[1][1], 0, 0, 0);
        }
    }

    // ---- epilogue: C/D layout col=lane&31, row=(reg&3)+8*(reg>>2)+4*(lane>>5) ----
    float* obase = out + (isQ ? (size_t)0 : (size_t)BB * LL * HH * RR);
    size_t c0 = ((size_t)(b * 1024 + l0) * 8 + h) * 128;
    #pragma unroll
    for (int mt = 0; mt < 2; mt++) {
        #pragma unroll
        for (int nt = 0; nt < 2; nt++) {
            int rb = wm * 64 + mt * 32 + 4 * (lane >> 5);
            int col = wn * 64 + nt * 32 + (lane & 31);
            #pragma unroll
            for (int reg = 0; reg < 16; reg++) {
                int rowt = rb + (reg & 3) + 8 * (reg >> 2);
                obase[c0 + (size_t)rowt * 1024 + col] = acc[mt][nt][reg];
            }
        }
    }
}

extern "C" void kernel_launch(void* const* d_in, const int* in_sizes, int n_in,
                              void* d_out, int out_size, void* d_ws, size_t ws_size,
                              hipStream_t stream) {
    const float* queries = (const float*)d_in[0];
    const float* keys    = (const float*)d_in[1];
    const float* freqs   = (const float*)d_in[2];
    const float* offsets = (const float*)d_in[3];
    const float* gains   = (const float*)d_in[4];
    const float* z       = (const float*)d_in[5];
    float* out = (float*)d_out;

    float* frp  = (float*)d_ws;                    // 5120 f32
    float* offp = frp + 5120;                      // 5120 f32
    unsigned short* zt = (unsigned short*)(offp + 5120);  // 2.62M bf16 (5.24 MB)

    prep_params<<<20, 256, 0, stream>>>(freqs, offsets, frp, offp);
    prep_z<<<320, 256, 0, stream>>>(gains, z, zt);
    spe_gemm<<<256, 256, 0, stream>>>(queries, keys, frp, offp, zt, out);
}